// Round 1
// baseline (361.021 us; speedup 1.0000x reference)
//
#include <hip/hip_runtime.h>

#define N 100000
#define E 1000000
#define ETOT 1100000   // E + N self-loops
#define NB1 391        // ceil(N/256)
#define NBE 4297       // ceil(ETOT/256)
#define NBH (NBE * 8)  // bucketed-hist blocks
#define NBG 782        // ceil(N/128) gemm1 blocks
#define BUCKET 12500   // N/8 — dst range per XCD bucket

typedef __attribute__((ext_vector_type(8))) short bf16x8;
typedef __attribute__((ext_vector_type(4))) float f32x4;
typedef __attribute__((ext_vector_type(2))) float f32x2;

__device__ __forceinline__ float lrelu(float x) { return x > 0.f ? x : 0.2f * x; }
// f32 -> bf16 bits, round-to-nearest-even
__device__ __forceinline__ unsigned short f2b(float x) {
    unsigned u = __float_as_uint(x);
    return (unsigned short)((u + 0x7FFFu + ((u >> 16) & 1u)) >> 16);
}
__device__ __forceinline__ float b2f(unsigned short v) {
    return __uint_as_float(((unsigned)v) << 16);
}
// f32 -> fp8 e4m3 (OCP), HW round-to-nearest-even
__device__ __forceinline__ unsigned char f2q(float x) {
    return (unsigned char)(__builtin_amdgcn_cvt_pk_fp8_f32(x, x, 0, false) & 0xFF);
}

// ---------------- CSR histogram (XCD-bucketed, R14 transform) + weight prep ----------------
// blocks 0..NBH-1: hist — block b handles edge window b>>3, dst bucket b&7.
// With round-robin blockIdx%8 -> XCD, hist bucket k (50 KB) is atomically
// updated only from XCD k: no cross-XCD line bouncing / writeback amplification.
__global__ __launch_bounds__(256) void prep_kernel(const int* __restrict__ ei,
                                                   int* __restrict__ hist,
                                                   const float* __restrict__ W1,
                                                   const float* __restrict__ W2,
                                                   const float* __restrict__ att_src1,
                                                   const float* __restrict__ att_dst1,
                                                   unsigned short* __restrict__ W1T,
                                                   unsigned short* __restrict__ W2T) {
    const int b = blockIdx.x;
    const int t = threadIdx.x;
    if (b < NBH) {
        const int w = b >> 3;
        const int k = b & 7;
        const int e = w * 256 + t;
        if (e < ETOT) {
            int d = (e < E) ? ei[E + e] : (e - E);
            if (d / BUCKET == k) atomicAdd(&hist[d], 1);
        }
        return;
    }
    const int bb = b - NBH;
    if (bb < 128) {
        W1T[(size_t)t * 128 + bb] = f2b(W1[(size_t)bb * 256 + t]);
    } else if (bb < 160) {
        int n = bb - 128;
        W2T[(size_t)n * 256 + t] = f2b(W2[(size_t)t * 32 + n]);
    } else {
        int idx = (bb - 160) * 256 + t;         // 0..2047
        int col = idx >> 7;                     // 0..15
        int k = idx & 127;
        int h = col & 7;
        const float* att = (col < 8) ? att_src1 : att_dst1;
        float acc = 0.f;
#pragma unroll 8
        for (int j = 0; j < 32; j++) acc += W1[(size_t)k * 256 + h * 32 + j] * att[h * 32 + j];
        W1T[(size_t)(256 + col) * 128 + k] = f2b(acc);
    }
}

// ---------------- merged: layer-1 GEMM (blocks 0..NBG-1) + scan1 (blocks NBG..) ----------------
// h1 is stored fp8 e4m3 (storage-only quantization; f32 accumulate downstream)
__global__ __launch_bounds__(256) void g1s_kernel(const float* __restrict__ x0,
                                                  const unsigned short* __restrict__ W1T,
                                                  unsigned char* __restrict__ h1,
                                                  float* __restrict__ a_src,
                                                  float* __restrict__ a_dst,
                                                  const int* __restrict__ hist,
                                                  int* __restrict__ rofs,
                                                  int* __restrict__ bsum) {
    __shared__ int sm[256];
    if (blockIdx.x >= NBG) {
        // ---- scan1: block-local exclusive scan of hist ----
        const int blk = blockIdx.x - NBG;
        const int t = threadIdx.x;
        const int i = blk * 256 + t;
        int v = (i < N) ? hist[i] : 0;
        sm[t] = v;
        __syncthreads();
#pragma unroll
        for (int off = 1; off < 256; off <<= 1) {
            int x = (t >= off) ? sm[t - off] : 0;
            __syncthreads();
            sm[t] += x;
            __syncthreads();
        }
        if (i < N) rofs[i] = sm[t] - v;
        if (t == 255) bsum[blk] = sm[255];
        return;
    }
    // ---- gemm1: h1 = x0 @ W1 (+ fused logits via fold tile) ----
    const int wv = threadIdx.x >> 6;
    const int lane = threadIdx.x & 63;
    const int quad = lane >> 4, c = lane & 15;
    const int base_m = blockIdx.x * 128 + wv * 32;
    bf16x8 af[2][4];
#pragma unroll
    for (int mt = 0; mt < 2; mt++) {
        int row = base_m + mt * 16 + c;
        int rowc = row < N ? row : N - 1;
        const float* ap = x0 + (size_t)rowc * 128 + quad * 8;
#pragma unroll
        for (int ks = 0; ks < 4; ks++) {
            float4 lo = *(const float4*)(ap + ks * 32);
            float4 hi = *(const float4*)(ap + ks * 32 + 4);
            bf16x8 f;
            f[0] = (short)f2b(lo.x); f[1] = (short)f2b(lo.y);
            f[2] = (short)f2b(lo.z); f[3] = (short)f2b(lo.w);
            f[4] = (short)f2b(hi.x); f[5] = (short)f2b(hi.y);
            f[6] = (short)f2b(hi.z); f[7] = (short)f2b(hi.w);
            af[mt][ks] = f;
        }
    }
    for (int nt = 0; nt < 17; nt++) {
        f32x4 acc0 = {0.f, 0.f, 0.f, 0.f};
        f32x4 acc1 = {0.f, 0.f, 0.f, 0.f};
#pragma unroll
        for (int ks = 0; ks < 4; ks++) {
            bf16x8 bf = *(const bf16x8*)(W1T + (size_t)(nt * 16 + c) * 128 + ks * 32 + quad * 8);
            acc0 = __builtin_amdgcn_mfma_f32_16x16x32_bf16(af[0][ks], bf, acc0, 0, 0, 0);
            acc1 = __builtin_amdgcn_mfma_f32_16x16x32_bf16(af[1][ks], bf, acc1, 0, 0, 0);
        }
        if (nt < 16) {
            const int col = nt * 16 + c;
#pragma unroll
            for (int r = 0; r < 4; r++) {
                int row0 = base_m + quad * 4 + r;
                if (row0 < N) h1[(size_t)row0 * 256 + col] = f2q(acc0[r]);
                int row1 = base_m + 16 + quad * 4 + r;
                if (row1 < N) h1[(size_t)row1 * 256 + col] = f2q(acc1[r]);
            }
        } else {
            float* dst = (c < 8) ? a_src : a_dst;
            int hh = c & 7;
#pragma unroll
            for (int r = 0; r < 4; r++) {
                int row0 = base_m + quad * 4 + r;
                if (row0 < N) dst[(size_t)row0 * 8 + hh] = acc0[r];
                int row1 = base_m + 16 + quad * 4 + r;
                if (row1 < N) dst[(size_t)row1 * 8 + hh] = acc1[r];
            }
        }
    }
}

// ---------------- merged scan2+scan3: each block redundantly reduces the bsum prefix ----------------
__global__ __launch_bounds__(256) void scan23_kernel(int* __restrict__ rofs,
                                                     const int* __restrict__ bsum,
                                                     int* __restrict__ cursor) {
    __shared__ int red[4];
    const int blk = blockIdx.x;
    const int t = threadIdx.x;
    // prefix = sum of bsum[0..blk-1], computed by all 256 threads cooperatively
    int v = 0;
    for (int j = t; j < blk; j += 256) v += bsum[j];
#pragma unroll
    for (int off = 1; off < 64; off <<= 1) v += __shfl_xor(v, off, 64);
    if ((t & 63) == 0) red[t >> 6] = v;
    __syncthreads();
    const int prefix = (red[0] + red[1]) + (red[2] + red[3]);
    const int i = blk * 256 + t;
    if (i < N) {
        int r = rofs[i] + prefix;
        rofs[i] = r;
        cursor[i] = r;
    }
    if (i == 0) rofs[N] = ETOT;
}

// ---------------- scatter, XCD-bucketed (R14 win: kills 16x write amplification) ----------------
__global__ __launch_bounds__(256) void scatter_kernel(const int* __restrict__ ei,
                                                      int* __restrict__ cursor,
                                                      int* __restrict__ esrc) {
    const int w = blockIdx.x >> 3;
    const int k = blockIdx.x & 7;
    const int e = w * 256 + threadIdx.x;
    if (e >= ETOT) return;
    int s, d;
    if (e < E) { s = ei[e]; d = ei[E + e]; } else { s = d = e - E; }
    if (d / BUCKET != k) return;
    int pos = atomicAdd(&cursor[d], 1);
    esrc[pos] = s;
}

// ---------------- layer 1 aggregate v6: wave/node; 1 exp per 8 edges;
// 2 edges per load round (dwordx2, 8 B/lane): lanes 0-31 carry even edge slots,
// lanes 32-63 odd slots; lane (half,q) owns channels 8q..8q+7 of parity `half`.
// Halves the gather-instruction count (8 dword -> 4 dwordx2 per 8-edge group)
// and replaces 8 shfl + 8 readlane with 8 bpermutes on a shared index. ----------------
__global__ __launch_bounds__(256) void seg1_kernel(const int* __restrict__ esrc,
                                                   const int* __restrict__ rofs,
                                                   const float* __restrict__ a_src,
                                                   const float* __restrict__ a_dst,
                                                   const unsigned char* __restrict__ h1,
                                                   const float* __restrict__ b1,
                                                   unsigned short* __restrict__ x2) {
    const int n = (blockIdx.x * 256 + threadIdx.x) >> 6;   // wave-uniform node
    const int lane = threadIdx.x & 63;
    const int e_pa = lane >> 3;          // phase-A edge slot 0..7
    const int h_pa = lane & 7;           // phase-A head
    const int half = lane >> 5;          // phase-B edge parity (0: even slots, 1: odd)
    const int q = lane & 31;             // phase-B channel group: ch 8q..8q+7
    // source lane for round r is wl + 16r: slot 2r+half, head q>>2 (that lane's
    // s8 is the slot's src node; its w is the weight for my channels' head)
    const int wl = ((lane & 32) >> 2) + ((lane & 28) >> 2);
    const int rs = __builtin_amdgcn_readfirstlane(rofs[n]);
    const int re = __builtin_amdgcn_readfirstlane(rofs[n + 1]);
    const float ad_pa = a_dst[(size_t)n * 8 + h_pa];
    float dsum = 0.f;
    float A[8] = {0, 0, 0, 0, 0, 0, 0, 0};
    for (int j0 = rs; j0 < re; j0 += 8) {
        // phase A: weights for 8 edges x 8 heads, ONE v_exp per lane
        int jm = j0 + e_pa;
        int jc = jm < re ? jm : re - 1;
        int s8 = esrc[jc];
        float av = a_src[(size_t)s8 * 8 + h_pa];
        float ex = __expf(lrelu(av + ad_pa));
        float w = (jm < re) ? ex : 0.f;
        dsum += w;
        // phase B: 4 rounds, 2 edges per round (dead edges clamp to re-1, w=0 masks)
#pragma unroll
        for (int r = 0; r < 4; r++) {
            int se = __shfl(s8, wl + 16 * r, 64);
            float wb = __shfl(w, wl + 16 * r, 64);
            uint2 hv = *(const uint2*)(h1 + (size_t)se * 256 + q * 8);
            f32x2 p0 = __builtin_amdgcn_cvt_pk_f32_fp8(hv.x, false);
            f32x2 p1 = __builtin_amdgcn_cvt_pk_f32_fp8(hv.x, true);
            f32x2 p2 = __builtin_amdgcn_cvt_pk_f32_fp8(hv.y, false);
            f32x2 p3 = __builtin_amdgcn_cvt_pk_f32_fp8(hv.y, true);
            A[0] += wb * p0[0]; A[1] += wb * p0[1];
            A[2] += wb * p1[0]; A[3] += wb * p1[1];
            A[4] += wb * p2[0]; A[5] += wb * p2[1];
            A[6] += wb * p3[0]; A[7] += wb * p3[1];
        }
    }
    // reduce dsum over the 8 edge slots -> every lane holds den for head lane&7
    dsum += __shfl_xor(dsum, 8, 64);
    dsum += __shfl_xor(dsum, 16, 64);
    dsum += __shfl_xor(dsum, 32, 64);
    float den = __shfl(dsum, q >> 2, 64);    // den for my channels' head
    // combine parity halves: T[k] = even-slot partial + odd-slot partial
    float T[8];
#pragma unroll
    for (int k = 0; k < 8; k++) T[k] = A[k] + __shfl_xor(A[k], 32, 64);
    // lane stores channels 8q + 4*half .. +3 (8 B, coalesced 512 B row)
    float s0 = half ? T[4] : T[0];
    float s1 = half ? T[5] : T[1];
    float s2 = half ? T[6] : T[2];
    float s3 = half ? T[7] : T[3];
    const float inv = 1.0f / den;
    float4 bb = *(const float4*)(b1 + 8 * q + 4 * half);
    float vx = s0 * inv + bb.x, vy = s1 * inv + bb.y;
    float vz = s2 * inv + bb.z, vw = s3 * inv + bb.w;
    vx = vx > 0.f ? vx : 0.f; vy = vy > 0.f ? vy : 0.f;
    vz = vz > 0.f ? vz : 0.f; vw = vw > 0.f ? vw : 0.f;
    ushort4 o = {f2b(vx), f2b(vy), f2b(vz), f2b(vw)};
    *(ushort4*)(x2 + (size_t)n * 256 + 8 * q + 4 * half) = o;
}

// ---------------- layer 2 GEMM via MFMA: h2 = x2 @ W2 (256->32), fused logits ----------------
__global__ __launch_bounds__(256) void gemm2_kernel(const unsigned short* __restrict__ x2,
                                                    const unsigned short* __restrict__ W2T,
                                                    const float* __restrict__ att_src2,
                                                    const float* __restrict__ att_dst2,
                                                    unsigned short* __restrict__ h2,
                                                    float* __restrict__ a_src2,
                                                    float* __restrict__ a_dst2) {
    const int wv = threadIdx.x >> 6;
    const int lane = threadIdx.x & 63;
    const int quad = lane >> 4, c = lane & 15;
    const int base_m = blockIdx.x * 128 + wv * 32;
    f32x4 acc[2][2] = {{{0, 0, 0, 0}, {0, 0, 0, 0}}, {{0, 0, 0, 0}, {0, 0, 0, 0}}};
#pragma unroll
    for (int ks = 0; ks < 8; ks++) {
        bf16x8 b0 = *(const bf16x8*)(W2T + (size_t)c * 256 + ks * 32 + quad * 8);
        bf16x8 b1 = *(const bf16x8*)(W2T + (size_t)(16 + c) * 256 + ks * 32 + quad * 8);
#pragma unroll
        for (int mt = 0; mt < 2; mt++) {
            int row = base_m + mt * 16 + c;
            int rowc = row < N ? row : N - 1;
            bf16x8 a = *(const bf16x8*)(x2 + (size_t)rowc * 256 + ks * 32 + quad * 8);
            acc[mt][0] = __builtin_amdgcn_mfma_f32_16x16x32_bf16(a, b0, acc[mt][0], 0, 0, 0);
            acc[mt][1] = __builtin_amdgcn_mfma_f32_16x16x32_bf16(a, b1, acc[mt][1], 0, 0, 0);
        }
    }
    float as0 = att_src2[c], as1 = att_src2[16 + c];
    float ad0 = att_dst2[c], ad1 = att_dst2[16 + c];
#pragma unroll
    for (int mt = 0; mt < 2; mt++) {
#pragma unroll
        for (int r = 0; r < 4; r++) {
            int row = base_m + mt * 16 + quad * 4 + r;
            float v0 = acc[mt][0][r], v1 = acc[mt][1][r];
            float ps = v0 * as0 + v1 * as1;
            float pd = v0 * ad0 + v1 * ad1;
#pragma unroll
            for (int off = 1; off < 16; off <<= 1) {
                ps += __shfl_xor(ps, off, 64);
                pd += __shfl_xor(pd, off, 64);
            }
            if (row < N) {
                h2[(size_t)row * 32 + c] = f2b(v0);
                h2[(size_t)row * 32 + 16 + c] = f2b(v1);
                if (c == 0) { a_src2[row] = ps; a_dst2[row] = pd; }
            }
        }
    }
}

// ---------------- layer 2 aggregate v4 + fused final: half-wave/node, 8 chains,
// exp deduplicated (lane l computes edge l&7 only; shfl broadcast) ----------------
__global__ __launch_bounds__(256) void seg2_kernel(const int* __restrict__ esrc,
                                                   const int* __restrict__ rofs,
                                                   const float* __restrict__ a_src2,
                                                   const float* __restrict__ a_dst2,
                                                   const unsigned short* __restrict__ h2,
                                                   const float* __restrict__ b2,
                                                   const float* __restrict__ linW,
                                                   const float* __restrict__ linb,
                                                   float* __restrict__ out) {
    __shared__ float lws[32 * 41];   // stride 41 breaks the 40-stride bank pattern
    __shared__ float vbuf[8][33];
    const int t = threadIdx.x;
    for (int i = t; i < 1280; i += 256) {
        int ci = i / 40, o = i - ci * 40;
        lws[ci * 41 + o] = linW[i];
    }
    const int n8 = t >> 5;
    const int c = t & 31;
    const int myk = t & 7;          // the one edge slot this lane computes exp for
    const int n = blockIdx.x * 8 + n8;      // N % 8 == 0 -> always valid
    const int rs = rofs[n], re = rofs[n + 1];
    const float ad = a_dst2[n];
    float dsum = 0.f;
    float A[8] = {0, 0, 0, 0, 0, 0, 0, 0};
    for (int j0 = rs; j0 < re; j0 += 8) {
        int sidx[8];
#pragma unroll
        for (int k = 0; k < 8; k++) {
            int j = j0 + k;
            sidx[k] = esrc[j < re ? j : re - 1];
        }
        // ONE exp per lane (edge myk); 4x dedup vs all-lanes-all-edges
        float av = a_src2[sidx[myk]];
        float myw = (j0 + myk < re) ? __expf(lrelu(av + ad)) : 0.f;
        dsum += myw;
        unsigned short hb[8];
#pragma unroll
        for (int k = 0; k < 8; k++) hb[k] = h2[(size_t)sidx[k] * 32 + c];
#pragma unroll
        for (int k = 0; k < 8; k++) {
            float w = __shfl(myw, (t & 32) + k, 64);   // broadcast within half-wave
            A[k] += w * b2f(hb[k]);
        }
    }
    // den = sum over the 8 myk groups (lanes l, l^1, l^2, l^4 span all k)
    dsum += __shfl_xor(dsum, 1, 64);
    dsum += __shfl_xor(dsum, 2, 64);
    dsum += __shfl_xor(dsum, 4, 64);
    float acc = ((A[0] + A[1]) + (A[2] + A[3])) + ((A[4] + A[5]) + (A[6] + A[7]));
    vbuf[n8][c] = acc / dsum + b2[c];
    __syncthreads();
    for (int idx = t; idx < 320; idx += 256) {
        int nn = idx / 40, o = idx - nn * 40;
        float s = linb[o];
#pragma unroll
        for (int ci = 0; ci < 32; ci++) s += vbuf[nn][ci] * lws[ci * 41 + o];
        out[(size_t)blockIdx.x * 320 + idx] = s;
    }
}

extern "C" void kernel_launch(void* const* d_in, const int* in_sizes, int n_in,
                              void* d_out, int out_size, void* d_ws, size_t ws_size,
                              hipStream_t stream) {
    const float* x0       = (const float*)d_in[0];
    const float* W1       = (const float*)d_in[1];
    const float* att_src1 = (const float*)d_in[2];
    const float* att_dst1 = (const float*)d_in[3];
    const float* b1       = (const float*)d_in[4];
    const float* W2       = (const float*)d_in[5];
    const float* att_src2 = (const float*)d_in[6];
    const float* att_dst2 = (const float*)d_in[7];
    const float* b2       = (const float*)d_in[8];
    const float* linW     = (const float*)d_in[9];
    const float* linb     = (const float*)d_in[10];
    const int*   ei       = (const int*)d_in[11];
    float* out = (float*)d_out;
    float* ws  = (float*)d_ws;

    unsigned char* h1    = (unsigned char*)ws;                   // 25.6M fp8 = 6.4M floats
    unsigned short* x2   = (unsigned short*)(ws + 6400000);      // 25.6M bf16 = 12.8M floats
    float* a_src1        = ws + 19200000;                        // 0.8M
    float* a_dst1        = ws + 20000000;                        // 0.8M
    unsigned short* h2   = (unsigned short*)(ws + 20800000);     // 3.2M bf16 = 1.6M floats
    float* a_src2        = ws + 22400000;                        // 0.1M
    float* a_dst2        = ws + 22500000;                        // 0.1M
    unsigned short* W1T  = (unsigned short*)(ws + 22600000);     // 272*128 bf16
    unsigned short* W2T  = (unsigned short*)(ws + 22620000);     // 32*256 bf16
    int*   hist          = (int*)(ws + 22630000);                // 0.1M
    int*   rofs          = (int*)(ws + 22730000);                // N+1
    int*   cursor        = (int*)(ws + 22840000);                // 0.1M
    int*   bsum          = (int*)(ws + 22940000);                // 512
    int*   esrc          = (int*)(ws + 22941000);                // 1.1M

    hipMemsetAsync(hist, 0, (size_t)N * 4, stream);

    // XCD-bucketed hist + weight prep
    prep_kernel<<<NBH + 168, 256, 0, stream>>>(ei, hist, W1, W2, att_src1, att_dst1, W1T, W2T);
    // merged gemm1 + scan1 (both depend only on prep; scan1 is atomic-free and tiny)
    g1s_kernel<<<NBG + NB1, 256, 0, stream>>>(x0, W1T, h1, a_src1, a_dst1, hist, rofs, bsum);
    // merged scan2+scan3: per-block redundant bsum prefix reduction
    scan23_kernel<<<NB1, 256, 0, stream>>>(rofs, bsum, cursor);
    // XCD-bucketed scatter: 8 blocks per edge window, bucket = blockIdx & 7
    scatter_kernel<<<NBE * 8, 256, 0, stream>>>(ei, cursor, esrc);

    seg1_kernel<<<N / 4, 256, 0, stream>>>(esrc, rofs, a_src1, a_dst1, h1, b1, x2);
    gemm2_kernel<<<(N + 127) / 128, 256, 0, stream>>>(x2, W2T, att_src2, att_dst2, h2, a_src2, a_dst2);
    seg2_kernel<<<N / 8, 256, 0, stream>>>(esrc, rofs, a_src2, a_dst2, h2, b2, linW, linb, out);
}

// Round 2
// 360.774 us; speedup vs baseline: 1.0007x; 1.0007x over previous
//
#include <hip/hip_runtime.h>

#define N 100000
#define E 1000000
#define ETOT 1100000   // E + N self-loops
#define NB1 391        // ceil(N/256)
#define NBE 4297       // ceil(ETOT/256)
#define NBH (NBE * 8)  // bucketed-hist blocks
#define NBG 782        // ceil(N/128) gemm1 blocks
#define BUCKET 12500   // N/8 — dst range per XCD bucket

typedef __attribute__((ext_vector_type(8))) short bf16x8;
typedef __attribute__((ext_vector_type(4))) float f32x4;
typedef __attribute__((ext_vector_type(2))) float f32x2;

__device__ __forceinline__ float lrelu(float x) { return x > 0.f ? x : 0.2f * x; }
// f32 -> bf16 bits, round-to-nearest-even
__device__ __forceinline__ unsigned short f2b(float x) {
    unsigned u = __float_as_uint(x);
    return (unsigned short)((u + 0x7FFFu + ((u >> 16) & 1u)) >> 16);
}
__device__ __forceinline__ float b2f(unsigned short v) {
    return __uint_as_float(((unsigned)v) << 16);
}
// f32 -> fp8 e4m3 (OCP), HW round-to-nearest-even
__device__ __forceinline__ unsigned char f2q(float x) {
    return (unsigned char)(__builtin_amdgcn_cvt_pk_fp8_f32(x, x, 0, false) & 0xFF);
}

// ---------------- CSR histogram (XCD-bucketed, R14 transform) + weight prep ----------------
// blocks 0..NBH-1: hist — block b handles edge window b>>3, dst bucket b&7.
// With round-robin blockIdx%8 -> XCD, hist bucket k (50 KB) is atomically
// updated only from XCD k: no cross-XCD line bouncing / writeback amplification.
__global__ __launch_bounds__(256) void prep_kernel(const int* __restrict__ ei,
                                                   int* __restrict__ hist,
                                                   const float* __restrict__ W1,
                                                   const float* __restrict__ W2,
                                                   const float* __restrict__ att_src1,
                                                   const float* __restrict__ att_dst1,
                                                   unsigned short* __restrict__ W1T,
                                                   unsigned short* __restrict__ W2T) {
    const int b = blockIdx.x;
    const int t = threadIdx.x;
    if (b < NBH) {
        const int w = b >> 3;
        const int k = b & 7;
        const int e = w * 256 + t;
        if (e < ETOT) {
            int d = (e < E) ? ei[E + e] : (e - E);
            if (d / BUCKET == k) atomicAdd(&hist[d], 1);
        }
        return;
    }
    const int bb = b - NBH;
    if (bb < 128) {
        W1T[(size_t)t * 128 + bb] = f2b(W1[(size_t)bb * 256 + t]);
    } else if (bb < 160) {
        int n = bb - 128;
        W2T[(size_t)n * 256 + t] = f2b(W2[(size_t)t * 32 + n]);
    } else {
        int idx = (bb - 160) * 256 + t;         // 0..2047
        int col = idx >> 7;                     // 0..15
        int k = idx & 127;
        int h = col & 7;
        const float* att = (col < 8) ? att_src1 : att_dst1;
        float acc = 0.f;
#pragma unroll 8
        for (int j = 0; j < 32; j++) acc += W1[(size_t)k * 256 + h * 32 + j] * att[h * 32 + j];
        W1T[(size_t)(256 + col) * 128 + k] = f2b(acc);
    }
}

// ---------------- merged: layer-1 GEMM (blocks 0..NBG-1) + scan1 (blocks NBG..) ----------------
// h1 is stored fp8 e4m3 (storage-only quantization; f32 accumulate downstream)
// Epilogue v2: packed cvt_pk_fp8 pairs + in-register 4x4 byte transpose
// (2 shfl_xor + 2 v_perm per tile) -> ONE dword store per lane per tile
// instead of 4 byte-stores. 128 -> 32 store instructions per lane.
__global__ __launch_bounds__(256) void g1s_kernel(const float* __restrict__ x0,
                                                  const unsigned short* __restrict__ W1T,
                                                  unsigned char* __restrict__ h1,
                                                  float* __restrict__ a_src,
                                                  float* __restrict__ a_dst,
                                                  const int* __restrict__ hist,
                                                  int* __restrict__ rofs,
                                                  int* __restrict__ bsum) {
    __shared__ int sm[256];
    if (blockIdx.x >= NBG) {
        // ---- scan1: block-local exclusive scan of hist ----
        const int blk = blockIdx.x - NBG;
        const int t = threadIdx.x;
        const int i = blk * 256 + t;
        int v = (i < N) ? hist[i] : 0;
        sm[t] = v;
        __syncthreads();
#pragma unroll
        for (int off = 1; off < 256; off <<= 1) {
            int x = (t >= off) ? sm[t - off] : 0;
            __syncthreads();
            sm[t] += x;
            __syncthreads();
        }
        if (i < N) rofs[i] = sm[t] - v;
        if (t == 255) bsum[blk] = sm[255];
        return;
    }
    // ---- gemm1: h1 = x0 @ W1 (+ fused logits via fold tile) ----
    const int wv = threadIdx.x >> 6;
    const int lane = threadIdx.x & 63;
    const int quad = lane >> 4, c = lane & 15;
    const int base_m = blockIdx.x * 128 + wv * 32;
    // byte-transpose selectors (l = position within 4-lane group)
    const int l = c & 3;
    const unsigned sel1 = (l & 1) ? 0x07030501u : 0x02060004u;
    const unsigned sel2 = (l & 2) ? 0x07060302u : 0x01000504u;
    bf16x8 af[2][4];
#pragma unroll
    for (int mt = 0; mt < 2; mt++) {
        int row = base_m + mt * 16 + c;
        int rowc = row < N ? row : N - 1;
        const float* ap = x0 + (size_t)rowc * 128 + quad * 8;
#pragma unroll
        for (int ks = 0; ks < 4; ks++) {
            float4 lo = *(const float4*)(ap + ks * 32);
            float4 hi = *(const float4*)(ap + ks * 32 + 4);
            bf16x8 f;
            f[0] = (short)f2b(lo.x); f[1] = (short)f2b(lo.y);
            f[2] = (short)f2b(lo.z); f[3] = (short)f2b(lo.w);
            f[4] = (short)f2b(hi.x); f[5] = (short)f2b(hi.y);
            f[6] = (short)f2b(hi.z); f[7] = (short)f2b(hi.w);
            af[mt][ks] = f;
        }
    }
    for (int nt = 0; nt < 17; nt++) {
        f32x4 acc0 = {0.f, 0.f, 0.f, 0.f};
        f32x4 acc1 = {0.f, 0.f, 0.f, 0.f};
#pragma unroll
        for (int ks = 0; ks < 4; ks++) {
            bf16x8 bf = *(const bf16x8*)(W1T + (size_t)(nt * 16 + c) * 128 + ks * 32 + quad * 8);
            acc0 = __builtin_amdgcn_mfma_f32_16x16x32_bf16(af[0][ks], bf, acc0, 0, 0, 0);
            acc1 = __builtin_amdgcn_mfma_f32_16x16x32_bf16(af[1][ks], bf, acc1, 0, 0, 0);
        }
        if (nt < 16) {
            const int colb = nt * 16 + (c & 12);
            // pack this lane's 4-row fp8 column into one u32 (bytes r0..r3)
            unsigned w0 = __builtin_amdgcn_cvt_pk_fp8_f32(acc0[0], acc0[1], 0u, false);
            w0 = __builtin_amdgcn_cvt_pk_fp8_f32(acc0[2], acc0[3], w0, true);
            unsigned w1 = __builtin_amdgcn_cvt_pk_fp8_f32(acc1[0], acc1[1], 0u, false);
            w1 = __builtin_amdgcn_cvt_pk_fp8_f32(acc1[2], acc1[3], w1, true);
            // 4x4 byte transpose within each 4-lane group: after this, lane
            // (quad,c) holds row base+quad*4+l, cols colb..colb+3
            unsigned p0 = (unsigned)__shfl_xor((int)w0, 1, 64);
            unsigned p1 = (unsigned)__shfl_xor((int)w1, 1, 64);
            unsigned x0t = __builtin_amdgcn_perm(w0, p0, sel1);
            unsigned x1t = __builtin_amdgcn_perm(w1, p1, sel1);
            unsigned q0 = (unsigned)__shfl_xor((int)x0t, 2, 64);
            unsigned q1 = (unsigned)__shfl_xor((int)x1t, 2, 64);
            unsigned t0 = __builtin_amdgcn_perm(x0t, q0, sel2);
            unsigned t1 = __builtin_amdgcn_perm(x1t, q1, sel2);
            int r0 = base_m + quad * 4 + l;
            if (r0 < N) *(unsigned*)(h1 + (size_t)r0 * 256 + colb) = t0;
            int r1 = base_m + 16 + quad * 4 + l;
            if (r1 < N) *(unsigned*)(h1 + (size_t)r1 * 256 + colb) = t1;
        } else {
            float* dst = (c < 8) ? a_src : a_dst;
            int hh = c & 7;
#pragma unroll
            for (int r = 0; r < 4; r++) {
                int row0 = base_m + quad * 4 + r;
                if (row0 < N) dst[(size_t)row0 * 8 + hh] = acc0[r];
                int row1 = base_m + 16 + quad * 4 + r;
                if (row1 < N) dst[(size_t)row1 * 8 + hh] = acc1[r];
            }
        }
    }
}

// ---------------- merged scan2+scan3: each block redundantly reduces the bsum prefix ----------------
__global__ __launch_bounds__(256) void scan23_kernel(int* __restrict__ rofs,
                                                     const int* __restrict__ bsum,
                                                     int* __restrict__ cursor) {
    __shared__ int red[4];
    const int blk = blockIdx.x;
    const int t = threadIdx.x;
    // prefix = sum of bsum[0..blk-1], computed by all 256 threads cooperatively
    int v = 0;
    for (int j = t; j < blk; j += 256) v += bsum[j];
#pragma unroll
    for (int off = 1; off < 64; off <<= 1) v += __shfl_xor(v, off, 64);
    if ((t & 63) == 0) red[t >> 6] = v;
    __syncthreads();
    const int prefix = (red[0] + red[1]) + (red[2] + red[3]);
    const int i = blk * 256 + t;
    if (i < N) {
        int r = rofs[i] + prefix;
        rofs[i] = r;
        cursor[i] = r;
    }
    if (i == 0) rofs[N] = ETOT;
}

// ---------------- scatter, XCD-bucketed (R14 win: kills 16x write amplification) ----------------
__global__ __launch_bounds__(256) void scatter_kernel(const int* __restrict__ ei,
                                                      int* __restrict__ cursor,
                                                      int* __restrict__ esrc) {
    const int w = blockIdx.x >> 3;
    const int k = blockIdx.x & 7;
    const int e = w * 256 + threadIdx.x;
    if (e >= ETOT) return;
    int s, d;
    if (e < E) { s = ei[e]; d = ei[E + e]; } else { s = d = e - E; }
    if (d / BUCKET != k) return;
    int pos = atomicAdd(&cursor[d], 1);
    esrc[pos] = s;
}

// ---------------- layer 1 aggregate v5: wave/node; 1 exp per 8 edges; fp8 h1 gathers (4 B/lane) ----------------
__global__ __launch_bounds__(256) void seg1_kernel(const int* __restrict__ esrc,
                                                   const int* __restrict__ rofs,
                                                   const float* __restrict__ a_src,
                                                   const float* __restrict__ a_dst,
                                                   const unsigned char* __restrict__ h1,
                                                   const float* __restrict__ b1,
                                                   unsigned short* __restrict__ x2) {
    const int n = (blockIdx.x * 256 + threadIdx.x) >> 6;   // wave-uniform node
    const int lane = threadIdx.x & 63;
    const int e_pa = lane >> 3;          // phase-A edge slot 0..7
    const int h_pa = lane & 7;           // phase-A head
    const int hB = lane >> 3;            // phase-B/epilogue head
    const int rs = __builtin_amdgcn_readfirstlane(rofs[n]);
    const int re = __builtin_amdgcn_readfirstlane(rofs[n + 1]);
    const float ad_pa = a_dst[(size_t)n * 8 + h_pa];
    float dsum = 0.f;
    float4 Aa = {0, 0, 0, 0}, Ab = {0, 0, 0, 0};
    for (int j0 = rs; j0 < re; j0 += 8) {
        // phase A: weights for 8 edges x 8 heads, ONE v_exp
        int jm = j0 + e_pa;
        int jc = jm < re ? jm : re - 1;
        int s8 = esrc[jc];
        float av = a_src[(size_t)s8 * 8 + h_pa];
        float ex = __expf(lrelu(av + ad_pa));
        float w = (jm < re) ? ex : 0.f;
        dsum += w;
        // phase B: all 8 gathers issue unconditionally (dead edges clamp to re-1, w=0 masks)
#pragma unroll
        for (int e = 0; e < 8; e++) {
            float wb = __shfl(w, e * 8 + hB, 64);
            int se = __builtin_amdgcn_readlane(s8, e * 8);
            unsigned hv = ((const unsigned*)(h1 + (size_t)se * 256))[lane];
            f32x2 lo = __builtin_amdgcn_cvt_pk_f32_fp8(hv, false);
            f32x2 hi = __builtin_amdgcn_cvt_pk_f32_fp8(hv, true);
            if (e & 1) {
                Ab.x += wb * lo[0]; Ab.y += wb * lo[1];
                Ab.z += wb * hi[0]; Ab.w += wb * hi[1];
            } else {
                Aa.x += wb * lo[0]; Aa.y += wb * lo[1];
                Aa.z += wb * hi[0]; Aa.w += wb * hi[1];
            }
        }
    }
    // reduce dsum over the 8 edge slots
    dsum += __shfl_xor(dsum, 8, 64);
    dsum += __shfl_xor(dsum, 16, 64);
    dsum += __shfl_xor(dsum, 32, 64);
    float den = __shfl(dsum, hB, 64);    // lane L<8 holds den for head L
    float4 acc = {Aa.x + Ab.x, Aa.y + Ab.y, Aa.z + Ab.z, Aa.w + Ab.w};
    const float inv = 1.0f / den;
    float4 bb = ((const float4*)b1)[lane];
    float vx = acc.x * inv + bb.x, vy = acc.y * inv + bb.y;
    float vz = acc.z * inv + bb.z, vw = acc.w * inv + bb.w;
    vx = vx > 0.f ? vx : 0.f; vy = vy > 0.f ? vy : 0.f;
    vz = vz > 0.f ? vz : 0.f; vw = vw > 0.f ? vw : 0.f;
    ushort4 o = {f2b(vx), f2b(vy), f2b(vz), f2b(vw)};
    ((ushort4*)(x2 + (size_t)n * 256))[lane] = o;
}

// ---------------- layer 2 GEMM via MFMA: h2 = x2 @ W2 (256->32), fused logits ----------------
__global__ __launch_bounds__(256) void gemm2_kernel(const unsigned short* __restrict__ x2,
                                                    const unsigned short* __restrict__ W2T,
                                                    const float* __restrict__ att_src2,
                                                    const float* __restrict__ att_dst2,
                                                    unsigned short* __restrict__ h2,
                                                    float* __restrict__ a_src2,
                                                    float* __restrict__ a_dst2) {
    const int wv = threadIdx.x >> 6;
    const int lane = threadIdx.x & 63;
    const int quad = lane >> 4, c = lane & 15;
    const int base_m = blockIdx.x * 128 + wv * 32;
    f32x4 acc[2][2] = {{{0, 0, 0, 0}, {0, 0, 0, 0}}, {{0, 0, 0, 0}, {0, 0, 0, 0}}};
#pragma unroll
    for (int ks = 0; ks < 8; ks++) {
        bf16x8 b0 = *(const bf16x8*)(W2T + (size_t)c * 256 + ks * 32 + quad * 8);
        bf16x8 b1 = *(const bf16x8*)(W2T + (size_t)(16 + c) * 256 + ks * 32 + quad * 8);
#pragma unroll
        for (int mt = 0; mt < 2; mt++) {
            int row = base_m + mt * 16 + c;
            int rowc = row < N ? row : N - 1;
            bf16x8 a = *(const bf16x8*)(x2 + (size_t)rowc * 256 + ks * 32 + quad * 8);
            acc[mt][0] = __builtin_amdgcn_mfma_f32_16x16x32_bf16(a, b0, acc[mt][0], 0, 0, 0);
            acc[mt][1] = __builtin_amdgcn_mfma_f32_16x16x32_bf16(a, b1, acc[mt][1], 0, 0, 0);
        }
    }
    float as0 = att_src2[c], as1 = att_src2[16 + c];
    float ad0 = att_dst2[c], ad1 = att_dst2[16 + c];
#pragma unroll
    for (int mt = 0; mt < 2; mt++) {
#pragma unroll
        for (int r = 0; r < 4; r++) {
            int row = base_m + mt * 16 + quad * 4 + r;
            float v0 = acc[mt][0][r], v1 = acc[mt][1][r];
            float ps = v0 * as0 + v1 * as1;
            float pd = v0 * ad0 + v1 * ad1;
#pragma unroll
            for (int off = 1; off < 16; off <<= 1) {
                ps += __shfl_xor(ps, off, 64);
                pd += __shfl_xor(pd, off, 64);
            }
            if (row < N) {
                h2[(size_t)row * 32 + c] = f2b(v0);
                h2[(size_t)row * 32 + 16 + c] = f2b(v1);
                if (c == 0) { a_src2[row] = ps; a_dst2[row] = pd; }
            }
        }
    }
}

// ---------------- layer 2 aggregate v4 + fused final: half-wave/node, 8 chains,
// exp deduplicated (lane l computes edge l&7 only; shfl broadcast) ----------------
__global__ __launch_bounds__(256) void seg2_kernel(const int* __restrict__ esrc,
                                                   const int* __restrict__ rofs,
                                                   const float* __restrict__ a_src2,
                                                   const float* __restrict__ a_dst2,
                                                   const unsigned short* __restrict__ h2,
                                                   const float* __restrict__ b2,
                                                   const float* __restrict__ linW,
                                                   const float* __restrict__ linb,
                                                   float* __restrict__ out) {
    __shared__ float lws[32 * 41];   // stride 41 breaks the 40-stride bank pattern
    __shared__ float vbuf[8][33];
    const int t = threadIdx.x;
    for (int i = t; i < 1280; i += 256) {
        int ci = i / 40, o = i - ci * 40;
        lws[ci * 41 + o] = linW[i];
    }
    const int n8 = t >> 5;
    const int c = t & 31;
    const int myk = t & 7;          // the one edge slot this lane computes exp for
    const int n = blockIdx.x * 8 + n8;      // N % 8 == 0 -> always valid
    const int rs = rofs[n], re = rofs[n + 1];
    const float ad = a_dst2[n];
    float dsum = 0.f;
    float A[8] = {0, 0, 0, 0, 0, 0, 0, 0};
    for (int j0 = rs; j0 < re; j0 += 8) {
        int sidx[8];
#pragma unroll
        for (int k = 0; k < 8; k++) {
            int j = j0 + k;
            sidx[k] = esrc[j < re ? j : re - 1];
        }
        // ONE exp per lane (edge myk); 4x dedup vs all-lanes-all-edges
        float av = a_src2[sidx[myk]];
        float myw = (j0 + myk < re) ? __expf(lrelu(av + ad)) : 0.f;
        dsum += myw;
        unsigned short hb[8];
#pragma unroll
        for (int k = 0; k < 8; k++) hb[k] = h2[(size_t)sidx[k] * 32 + c];
#pragma unroll
        for (int k = 0; k < 8; k++) {
            float w = __shfl(myw, (t & 32) + k, 64);   // broadcast within half-wave
            A[k] += w * b2f(hb[k]);
        }
    }
    // den = sum over the 8 myk groups (lanes l, l^1, l^2, l^4 span all k)
    dsum += __shfl_xor(dsum, 1, 64);
    dsum += __shfl_xor(dsum, 2, 64);
    dsum += __shfl_xor(dsum, 4, 64);
    float acc = ((A[0] + A[1]) + (A[2] + A[3])) + ((A[4] + A[5]) + (A[6] + A[7]));
    vbuf[n8][c] = acc / dsum + b2[c];
    __syncthreads();
    for (int idx = t; idx < 320; idx += 256) {
        int nn = idx / 40, o = idx - nn * 40;
        float s = linb[o];
#pragma unroll
        for (int ci = 0; ci < 32; ci++) s += vbuf[nn][ci] * lws[ci * 41 + o];
        out[(size_t)blockIdx.x * 320 + idx] = s;
    }
}

extern "C" void kernel_launch(void* const* d_in, const int* in_sizes, int n_in,
                              void* d_out, int out_size, void* d_ws, size_t ws_size,
                              hipStream_t stream) {
    const float* x0       = (const float*)d_in[0];
    const float* W1       = (const float*)d_in[1];
    const float* att_src1 = (const float*)d_in[2];
    const float* att_dst1 = (const float*)d_in[3];
    const float* b1       = (const float*)d_in[4];
    const float* W2       = (const float*)d_in[5];
    const float* att_src2 = (const float*)d_in[6];
    const float* att_dst2 = (const float*)d_in[7];
    const float* b2       = (const float*)d_in[8];
    const float* linW     = (const float*)d_in[9];
    const float* linb     = (const float*)d_in[10];
    const int*   ei       = (const int*)d_in[11];
    float* out = (float*)d_out;
    float* ws  = (float*)d_ws;

    unsigned char* h1    = (unsigned char*)ws;                   // 25.6M fp8 = 6.4M floats
    unsigned short* x2   = (unsigned short*)(ws + 6400000);      // 25.6M bf16 = 12.8M floats
    float* a_src1        = ws + 19200000;                        // 0.8M
    float* a_dst1        = ws + 20000000;                        // 0.8M
    unsigned short* h2   = (unsigned short*)(ws + 20800000);     // 3.2M bf16 = 1.6M floats
    float* a_src2        = ws + 22400000;                        // 0.1M
    float* a_dst2        = ws + 22500000;                        // 0.1M
    unsigned short* W1T  = (unsigned short*)(ws + 22600000);     // 272*128 bf16
    unsigned short* W2T  = (unsigned short*)(ws + 22620000);     // 32*256 bf16
    int*   hist          = (int*)(ws + 22630000);                // 0.1M
    int*   rofs          = (int*)(ws + 22730000);                // N+1
    int*   cursor        = (int*)(ws + 22840000);                // 0.1M
    int*   bsum          = (int*)(ws + 22940000);                // 512
    int*   esrc          = (int*)(ws + 22941000);                // 1.1M

    hipMemsetAsync(hist, 0, (size_t)N * 4, stream);

    // XCD-bucketed hist + weight prep
    prep_kernel<<<NBH + 168, 256, 0, stream>>>(ei, hist, W1, W2, att_src1, att_dst1, W1T, W2T);
    // merged gemm1 + scan1 (both depend only on prep; scan1 is atomic-free and tiny)
    g1s_kernel<<<NBG + NB1, 256, 0, stream>>>(x0, W1T, h1, a_src1, a_dst1, hist, rofs, bsum);
    // merged scan2+scan3: per-block redundant bsum prefix reduction
    scan23_kernel<<<NB1, 256, 0, stream>>>(rofs, bsum, cursor);
    // XCD-bucketed scatter: 8 blocks per edge window, bucket = blockIdx & 7
    scatter_kernel<<<NBE * 8, 256, 0, stream>>>(ei, cursor, esrc);

    seg1_kernel<<<N / 4, 256, 0, stream>>>(esrc, rofs, a_src1, a_dst1, h1, b1, x2);
    gemm2_kernel<<<(N + 127) / 128, 256, 0, stream>>>(x2, W2T, att_src2, att_dst2, h2, a_src2, a_dst2);
    seg2_kernel<<<N / 8, 256, 0, stream>>>(esrc, rofs, a_src2, a_dst2, h2, b2, linW, linb, out);
}

// Round 3
// 358.940 us; speedup vs baseline: 1.0058x; 1.0051x over previous
//
#include <hip/hip_runtime.h>

#define N 100000
#define E 1000000
#define ETOT 1100000   // E + N self-loops
#define NB1 391        // ceil(N/256)
#define NBE 4297       // ceil(ETOT/256)
#define NPREP 2048     // grid-stride blocks for hist/scatter (multiple of 8)
#define NBG 782        // ceil(N/128) gemm1 blocks
#define BUCKET 12500   // N/8 — dst range per XCD bucket

typedef __attribute__((ext_vector_type(8))) short bf16x8;
typedef __attribute__((ext_vector_type(4))) float f32x4;
typedef __attribute__((ext_vector_type(2))) float f32x2;

__device__ __forceinline__ float lrelu(float x) { return x > 0.f ? x : 0.2f * x; }
// f32 -> bf16 bits, round-to-nearest-even
__device__ __forceinline__ unsigned short f2b(float x) {
    unsigned u = __float_as_uint(x);
    return (unsigned short)((u + 0x7FFFu + ((u >> 16) & 1u)) >> 16);
}
__device__ __forceinline__ float b2f(unsigned short v) {
    return __uint_as_float(((unsigned)v) << 16);
}
// f32 -> fp8 e4m3 (OCP), HW round-to-nearest-even
__device__ __forceinline__ unsigned char f2q(float x) {
    return (unsigned char)(__builtin_amdgcn_cvt_pk_fp8_f32(x, x, 0, false) & 0xFF);
}

// ---------------- CSR histogram (XCD-bucketed, grid-strided) + weight prep ----------------
// blocks 0..NPREP-1: hist — block b handles bucket b&7, edge windows (b>>3)+256j.
// bucket = blockIdx&7 -> XCD b%8: hist bucket k (50 KB) is atomically updated
// only from XCD k. Grid-stride cuts block count 34376 -> 2048 (dispatch floor).
__global__ __launch_bounds__(256) void prep_kernel(const int* __restrict__ ei,
                                                   int* __restrict__ hist,
                                                   const float* __restrict__ W1,
                                                   const float* __restrict__ W2,
                                                   const float* __restrict__ att_src1,
                                                   const float* __restrict__ att_dst1,
                                                   unsigned short* __restrict__ W1T,
                                                   unsigned short* __restrict__ W2T) {
    const int b = blockIdx.x;
    const int t = threadIdx.x;
    if (b < NPREP) {
        const int k = b & 7;
        for (int w = b >> 3; w < NBE; w += 256) {
            const int e = w * 256 + t;
            if (e < ETOT) {
                int d = (e < E) ? ei[E + e] : (e - E);
                if (d / BUCKET == k) atomicAdd(&hist[d], 1);
            }
        }
        return;
    }
    const int bb = b - NPREP;
    if (bb < 128) {
        W1T[(size_t)t * 128 + bb] = f2b(W1[(size_t)bb * 256 + t]);
    } else if (bb < 160) {
        int n = bb - 128;
        W2T[(size_t)n * 256 + t] = f2b(W2[(size_t)t * 32 + n]);
    } else {
        int idx = (bb - 160) * 256 + t;         // 0..2047
        int col = idx >> 7;                     // 0..15
        int k = idx & 127;
        int h = col & 7;
        const float* att = (col < 8) ? att_src1 : att_dst1;
        float acc = 0.f;
#pragma unroll 8
        for (int j = 0; j < 32; j++) acc += W1[(size_t)k * 256 + h * 32 + j] * att[h * 32 + j];
        W1T[(size_t)(256 + col) * 128 + k] = f2b(acc);
    }
}

// ---------------- merged: layer-1 GEMM (blocks 0..NBG-1) + scan1 (blocks NBG..) ----------------
// h1 is stored fp8 e4m3 (storage-only quantization; f32 accumulate downstream)
// Epilogue: packed cvt_pk_fp8 pairs + in-register 4x4 byte transpose -> dword stores.
__global__ __launch_bounds__(256) void g1s_kernel(const float* __restrict__ x0,
                                                  const unsigned short* __restrict__ W1T,
                                                  unsigned char* __restrict__ h1,
                                                  float* __restrict__ a_src,
                                                  float* __restrict__ a_dst,
                                                  const int* __restrict__ hist,
                                                  int* __restrict__ rofs,
                                                  int* __restrict__ bsum) {
    __shared__ int sm[256];
    if (blockIdx.x >= NBG) {
        // ---- scan1: block-local exclusive scan of hist ----
        const int blk = blockIdx.x - NBG;
        const int t = threadIdx.x;
        const int i = blk * 256 + t;
        int v = (i < N) ? hist[i] : 0;
        sm[t] = v;
        __syncthreads();
#pragma unroll
        for (int off = 1; off < 256; off <<= 1) {
            int x = (t >= off) ? sm[t - off] : 0;
            __syncthreads();
            sm[t] += x;
            __syncthreads();
        }
        if (i < N) rofs[i] = sm[t] - v;
        if (t == 255) bsum[blk] = sm[255];
        return;
    }
    // ---- gemm1: h1 = x0 @ W1 (+ fused logits via fold tile) ----
    const int wv = threadIdx.x >> 6;
    const int lane = threadIdx.x & 63;
    const int quad = lane >> 4, c = lane & 15;
    const int base_m = blockIdx.x * 128 + wv * 32;
    // byte-transpose selectors (l = position within 4-lane group)
    const int l = c & 3;
    const unsigned sel1 = (l & 1) ? 0x07030501u : 0x02060004u;
    const unsigned sel2 = (l & 2) ? 0x07060302u : 0x01000504u;
    bf16x8 af[2][4];
#pragma unroll
    for (int mt = 0; mt < 2; mt++) {
        int row = base_m + mt * 16 + c;
        int rowc = row < N ? row : N - 1;
        const float* ap = x0 + (size_t)rowc * 128 + quad * 8;
#pragma unroll
        for (int ks = 0; ks < 4; ks++) {
            float4 lo = *(const float4*)(ap + ks * 32);
            float4 hi = *(const float4*)(ap + ks * 32 + 4);
            bf16x8 f;
            f[0] = (short)f2b(lo.x); f[1] = (short)f2b(lo.y);
            f[2] = (short)f2b(lo.z); f[3] = (short)f2b(lo.w);
            f[4] = (short)f2b(hi.x); f[5] = (short)f2b(hi.y);
            f[6] = (short)f2b(hi.z); f[7] = (short)f2b(hi.w);
            af[mt][ks] = f;
        }
    }
    for (int nt = 0; nt < 17; nt++) {
        f32x4 acc0 = {0.f, 0.f, 0.f, 0.f};
        f32x4 acc1 = {0.f, 0.f, 0.f, 0.f};
#pragma unroll
        for (int ks = 0; ks < 4; ks++) {
            bf16x8 bf = *(const bf16x8*)(W1T + (size_t)(nt * 16 + c) * 128 + ks * 32 + quad * 8);
            acc0 = __builtin_amdgcn_mfma_f32_16x16x32_bf16(af[0][ks], bf, acc0, 0, 0, 0);
            acc1 = __builtin_amdgcn_mfma_f32_16x16x32_bf16(af[1][ks], bf, acc1, 0, 0, 0);
        }
        if (nt < 16) {
            const int colb = nt * 16 + (c & 12);
            // pack this lane's 4-row fp8 column into one u32 (bytes r0..r3)
            unsigned w0 = __builtin_amdgcn_cvt_pk_fp8_f32(acc0[0], acc0[1], 0u, false);
            w0 = __builtin_amdgcn_cvt_pk_fp8_f32(acc0[2], acc0[3], w0, true);
            unsigned w1 = __builtin_amdgcn_cvt_pk_fp8_f32(acc1[0], acc1[1], 0u, false);
            w1 = __builtin_amdgcn_cvt_pk_fp8_f32(acc1[2], acc1[3], w1, true);
            // 4x4 byte transpose within each 4-lane group
            unsigned p0 = (unsigned)__shfl_xor((int)w0, 1, 64);
            unsigned p1 = (unsigned)__shfl_xor((int)w1, 1, 64);
            unsigned x0t = __builtin_amdgcn_perm(w0, p0, sel1);
            unsigned x1t = __builtin_amdgcn_perm(w1, p1, sel1);
            unsigned q0 = (unsigned)__shfl_xor((int)x0t, 2, 64);
            unsigned q1 = (unsigned)__shfl_xor((int)x1t, 2, 64);
            unsigned t0 = __builtin_amdgcn_perm(x0t, q0, sel2);
            unsigned t1 = __builtin_amdgcn_perm(x1t, q1, sel2);
            int r0 = base_m + quad * 4 + l;
            if (r0 < N) *(unsigned*)(h1 + (size_t)r0 * 256 + colb) = t0;
            int r1 = base_m + 16 + quad * 4 + l;
            if (r1 < N) *(unsigned*)(h1 + (size_t)r1 * 256 + colb) = t1;
        } else {
            float* dst = (c < 8) ? a_src : a_dst;
            int hh = c & 7;
#pragma unroll
            for (int r = 0; r < 4; r++) {
                int row0 = base_m + quad * 4 + r;
                if (row0 < N) dst[(size_t)row0 * 8 + hh] = acc0[r];
                int row1 = base_m + 16 + quad * 4 + r;
                if (row1 < N) dst[(size_t)row1 * 8 + hh] = acc1[r];
            }
        }
    }
}

// ---------------- merged scan2+scan3: each block redundantly reduces the bsum prefix ----------------
__global__ __launch_bounds__(256) void scan23_kernel(int* __restrict__ rofs,
                                                     const int* __restrict__ bsum,
                                                     int* __restrict__ cursor) {
    __shared__ int red[4];
    const int blk = blockIdx.x;
    const int t = threadIdx.x;
    // prefix = sum of bsum[0..blk-1], computed by all 256 threads cooperatively
    int v = 0;
    for (int j = t; j < blk; j += 256) v += bsum[j];
#pragma unroll
    for (int off = 1; off < 64; off <<= 1) v += __shfl_xor(v, off, 64);
    if ((t & 63) == 0) red[t >> 6] = v;
    __syncthreads();
    const int prefix = (red[0] + red[1]) + (red[2] + red[3]);
    const int i = blk * 256 + t;
    if (i < N) {
        int r = rofs[i] + prefix;
        rofs[i] = r;
        cursor[i] = r;
    }
    if (i == 0) rofs[N] = ETOT;
}

// ---------------- scatter, XCD-bucketed, grid-strided (2048 blocks) ----------------
__global__ __launch_bounds__(256) void scatter_kernel(const int* __restrict__ ei,
                                                      int* __restrict__ cursor,
                                                      int* __restrict__ esrc) {
    const int k = blockIdx.x & 7;
    for (int w = blockIdx.x >> 3; w < NBE; w += 256) {
        const int e = w * 256 + threadIdx.x;
        if (e >= ETOT) continue;
        int s, d;
        if (e < E) { s = ei[e]; d = ei[E + e]; } else { s = d = e - E; }
        if (d / BUCKET != k) continue;
        int pos = atomicAdd(&cursor[d], 1);
        esrc[pos] = s;
    }
}

// ---------------- fused layer-1 aggregate + layer-2 GEMM ----------------
// 1024 threads = 16 waves = 16 nodes per block. Each wave runs the seg1-v5 body
// and writes its x2 row to LDS (never to HBM: saves 51.2 MB write + 51.2 MB read
// and a whole dispatch). After the barrier, wave 0 runs the 16-row MFMA tile
// (h2 = relu_x2 @ W2, 256->32) + fused attention logits; waves 1..15 exit.
__global__ __launch_bounds__(1024, 8) void s1g2_kernel(const int* __restrict__ esrc,
                                                       const int* __restrict__ rofs,
                                                       const float* __restrict__ a_src,
                                                       const float* __restrict__ a_dst,
                                                       const unsigned char* __restrict__ h1,
                                                       const float* __restrict__ b1,
                                                       const unsigned short* __restrict__ W2T,
                                                       const float* __restrict__ att_src2,
                                                       const float* __restrict__ att_dst2,
                                                       unsigned short* __restrict__ h2,
                                                       float* __restrict__ a_src2,
                                                       float* __restrict__ a_dst2) {
    // 16 rows x 256 bf16, row stride 264 ushorts (528 B): dword-bank step 132%32=4
    // -> at most 2-way conflict on the MFMA A-reads (free).
    __shared__ unsigned short smx[16 * 264];
    const int wv = threadIdx.x >> 6;
    const int lane = threadIdx.x & 63;
    const int n = blockIdx.x * 16 + wv;          // N % 16 == 0 -> always valid
    const int e_pa = lane >> 3;          // phase-A edge slot 0..7
    const int h_pa = lane & 7;           // phase-A head
    const int hB = lane >> 3;            // phase-B/epilogue head
    const int rs = __builtin_amdgcn_readfirstlane(rofs[n]);
    const int re = __builtin_amdgcn_readfirstlane(rofs[n + 1]);
    const float ad_pa = a_dst[(size_t)n * 8 + h_pa];
    float dsum = 0.f;
    float4 Aa = {0, 0, 0, 0}, Ab = {0, 0, 0, 0};
    for (int j0 = rs; j0 < re; j0 += 8) {
        // phase A: weights for 8 edges x 8 heads, ONE v_exp
        int jm = j0 + e_pa;
        int jc = jm < re ? jm : re - 1;
        int s8 = esrc[jc];
        float av = a_src[(size_t)s8 * 8 + h_pa];
        float ex = __expf(lrelu(av + ad_pa));
        float w = (jm < re) ? ex : 0.f;
        dsum += w;
        // phase B: all 8 gathers issue unconditionally (dead edges clamp to re-1, w=0 masks)
#pragma unroll
        for (int e = 0; e < 8; e++) {
            float wb = __shfl(w, e * 8 + hB, 64);
            int se = __builtin_amdgcn_readlane(s8, e * 8);
            unsigned hv = ((const unsigned*)(h1 + (size_t)se * 256))[lane];
            f32x2 lo = __builtin_amdgcn_cvt_pk_f32_fp8(hv, false);
            f32x2 hi = __builtin_amdgcn_cvt_pk_f32_fp8(hv, true);
            if (e & 1) {
                Ab.x += wb * lo[0]; Ab.y += wb * lo[1];
                Ab.z += wb * hi[0]; Ab.w += wb * hi[1];
            } else {
                Aa.x += wb * lo[0]; Aa.y += wb * lo[1];
                Aa.z += wb * hi[0]; Aa.w += wb * hi[1];
            }
        }
    }
    // reduce dsum over the 8 edge slots
    dsum += __shfl_xor(dsum, 8, 64);
    dsum += __shfl_xor(dsum, 16, 64);
    dsum += __shfl_xor(dsum, 32, 64);
    float den = __shfl(dsum, hB, 64);    // lane L<8 holds den for head L
    float4 acc = {Aa.x + Ab.x, Aa.y + Ab.y, Aa.z + Ab.z, Aa.w + Ab.w};
    const float inv = 1.0f / den;
    float4 bb = ((const float4*)b1)[lane];
    float vx = acc.x * inv + bb.x, vy = acc.y * inv + bb.y;
    float vz = acc.z * inv + bb.z, vw = acc.w * inv + bb.w;
    vx = vx > 0.f ? vx : 0.f; vy = vy > 0.f ? vy : 0.f;
    vz = vz > 0.f ? vz : 0.f; vw = vw > 0.f ? vw : 0.f;
    ushort4 o = {f2b(vx), f2b(vy), f2b(vz), f2b(vw)};
    *(ushort4*)(smx + wv * 264 + lane * 4) = o;
    __syncthreads();
    if (threadIdx.x < 64) {
        // ---- gemm2 tile: 16 rows x (K=256) x 32 out, one wave ----
        const int quad = lane >> 4, c = lane & 15;
        const int base_m = blockIdx.x * 16;
        f32x4 g[2] = {{0, 0, 0, 0}, {0, 0, 0, 0}};
#pragma unroll
        for (int ks = 0; ks < 8; ks++) {
            bf16x8 a = *(const bf16x8*)(smx + c * 264 + ks * 32 + quad * 8);
            bf16x8 b0 = *(const bf16x8*)(W2T + (size_t)c * 256 + ks * 32 + quad * 8);
            bf16x8 b1v = *(const bf16x8*)(W2T + (size_t)(16 + c) * 256 + ks * 32 + quad * 8);
            g[0] = __builtin_amdgcn_mfma_f32_16x16x32_bf16(a, b0, g[0], 0, 0, 0);
            g[1] = __builtin_amdgcn_mfma_f32_16x16x32_bf16(a, b1v, g[1], 0, 0, 0);
        }
        float as0 = att_src2[c], as1 = att_src2[16 + c];
        float ad0 = att_dst2[c], ad1 = att_dst2[16 + c];
#pragma unroll
        for (int r = 0; r < 4; r++) {
            int row = base_m + quad * 4 + r;
            float v0 = g[0][r], v1 = g[1][r];
            float ps = v0 * as0 + v1 * as1;
            float pd = v0 * ad0 + v1 * ad1;
#pragma unroll
            for (int off = 1; off < 16; off <<= 1) {
                ps += __shfl_xor(ps, off, 64);
                pd += __shfl_xor(pd, off, 64);
            }
            h2[(size_t)row * 32 + c] = f2b(v0);
            h2[(size_t)row * 32 + 16 + c] = f2b(v1);
            if (c == 0) { a_src2[row] = ps; a_dst2[row] = pd; }
        }
    }
}

// ---------------- layer 2 aggregate v4 + fused final: half-wave/node, 8 chains,
// exp deduplicated (lane l computes edge l&7 only; shfl broadcast) ----------------
__global__ __launch_bounds__(256) void seg2_kernel(const int* __restrict__ esrc,
                                                   const int* __restrict__ rofs,
                                                   const float* __restrict__ a_src2,
                                                   const float* __restrict__ a_dst2,
                                                   const unsigned short* __restrict__ h2,
                                                   const float* __restrict__ b2,
                                                   const float* __restrict__ linW,
                                                   const float* __restrict__ linb,
                                                   float* __restrict__ out) {
    __shared__ float lws[32 * 41];   // stride 41 breaks the 40-stride bank pattern
    __shared__ float vbuf[8][33];
    const int t = threadIdx.x;
    for (int i = t; i < 1280; i += 256) {
        int ci = i / 40, o = i - ci * 40;
        lws[ci * 41 + o] = linW[i];
    }
    const int n8 = t >> 5;
    const int c = t & 31;
    const int myk = t & 7;          // the one edge slot this lane computes exp for
    const int n = blockIdx.x * 8 + n8;      // N % 8 == 0 -> always valid
    const int rs = rofs[n], re = rofs[n + 1];
    const float ad = a_dst2[n];
    float dsum = 0.f;
    float A[8] = {0, 0, 0, 0, 0, 0, 0, 0};
    for (int j0 = rs; j0 < re; j0 += 8) {
        int sidx[8];
#pragma unroll
        for (int k = 0; k < 8; k++) {
            int j = j0 + k;
            sidx[k] = esrc[j < re ? j : re - 1];
        }
        // ONE exp per lane (edge myk); 4x dedup vs all-lanes-all-edges
        float av = a_src2[sidx[myk]];
        float myw = (j0 + myk < re) ? __expf(lrelu(av + ad)) : 0.f;
        dsum += myw;
        unsigned short hb[8];
#pragma unroll
        for (int k = 0; k < 8; k++) hb[k] = h2[(size_t)sidx[k] * 32 + c];
#pragma unroll
        for (int k = 0; k < 8; k++) {
            float w = __shfl(myw, (t & 32) + k, 64);   // broadcast within half-wave
            A[k] += w * b2f(hb[k]);
        }
    }
    // den = sum over the 8 myk groups (lanes l, l^1, l^2, l^4 span all k)
    dsum += __shfl_xor(dsum, 1, 64);
    dsum += __shfl_xor(dsum, 2, 64);
    dsum += __shfl_xor(dsum, 4, 64);
    float acc = ((A[0] + A[1]) + (A[2] + A[3])) + ((A[4] + A[5]) + (A[6] + A[7]));
    vbuf[n8][c] = acc / dsum + b2[c];
    __syncthreads();
    for (int idx = t; idx < 320; idx += 256) {
        int nn = idx / 40, o = idx - nn * 40;
        float s = linb[o];
#pragma unroll
        for (int ci = 0; ci < 32; ci++) s += vbuf[nn][ci] * lws[ci * 41 + o];
        out[(size_t)blockIdx.x * 320 + idx] = s;
    }
}

extern "C" void kernel_launch(void* const* d_in, const int* in_sizes, int n_in,
                              void* d_out, int out_size, void* d_ws, size_t ws_size,
                              hipStream_t stream) {
    const float* x0       = (const float*)d_in[0];
    const float* W1       = (const float*)d_in[1];
    const float* att_src1 = (const float*)d_in[2];
    const float* att_dst1 = (const float*)d_in[3];
    const float* b1       = (const float*)d_in[4];
    const float* W2       = (const float*)d_in[5];
    const float* att_src2 = (const float*)d_in[6];
    const float* att_dst2 = (const float*)d_in[7];
    const float* b2       = (const float*)d_in[8];
    const float* linW     = (const float*)d_in[9];
    const float* linb     = (const float*)d_in[10];
    const int*   ei       = (const int*)d_in[11];
    float* out = (float*)d_out;
    float* ws  = (float*)d_ws;

    unsigned char* h1    = (unsigned char*)ws;                   // 25.6M fp8 = 6.4M floats
    // x2 slot (ws+6400000) now unused: x2 lives in LDS inside s1g2_kernel
    float* a_src1        = ws + 19200000;                        // 0.8M
    float* a_dst1        = ws + 20000000;                        // 0.8M
    unsigned short* h2   = (unsigned short*)(ws + 20800000);     // 3.2M bf16 = 1.6M floats
    float* a_src2        = ws + 22400000;                        // 0.1M
    float* a_dst2        = ws + 22500000;                        // 0.1M
    unsigned short* W1T  = (unsigned short*)(ws + 22600000);     // 272*128 bf16
    unsigned short* W2T  = (unsigned short*)(ws + 22620000);     // 32*256 bf16
    int*   hist          = (int*)(ws + 22630000);                // 0.1M
    int*   rofs          = (int*)(ws + 22730000);                // N+1
    int*   cursor        = (int*)(ws + 22840000);                // 0.1M
    int*   bsum          = (int*)(ws + 22940000);                // 512
    int*   esrc          = (int*)(ws + 22941000);                // 1.1M

    hipMemsetAsync(hist, 0, (size_t)N * 4, stream);

    // XCD-bucketed hist (grid-strided) + weight prep
    prep_kernel<<<NPREP + 168, 256, 0, stream>>>(ei, hist, W1, W2, att_src1, att_dst1, W1T, W2T);
    // merged gemm1 + scan1 (both depend only on prep; scan1 is atomic-free and tiny)
    g1s_kernel<<<NBG + NB1, 256, 0, stream>>>(x0, W1T, h1, a_src1, a_dst1, hist, rofs, bsum);
    // merged scan2+scan3: per-block redundant bsum prefix reduction
    scan23_kernel<<<NB1, 256, 0, stream>>>(rofs, bsum, cursor);
    // XCD-bucketed scatter, grid-strided
    scatter_kernel<<<NPREP, 256, 0, stream>>>(ei, cursor, esrc);
    // fused layer-1 aggregate + layer-2 GEMM (x2 stays in LDS)
    s1g2_kernel<<<N / 16, 1024, 0, stream>>>(esrc, rofs, a_src1, a_dst1, h1, b1,
                                             W2T, att_src2, att_dst2, h2, a_src2, a_dst2);
    seg2_kernel<<<N / 8, 256, 0, stream>>>(esrc, rofs, a_src2, a_dst2, h2, b2, linW, linb, out);
}